// Round 7
// baseline (432.962 us; speedup 1.0000x reference)
//
#include <hip/hip_runtime.h>
#include <math.h>

// QCQP via FISTA. One 1024-thread workgroup per batch.
// R5 post-mortem: with 512 threads the per-thread H slice (128 floats)
// can never fit the arch half of the 128V/128A split -> some array always
// lands in AGPRs -> ~500 cy/iter of shuttle issue; and 2 waves/SIMD can't
// hide the ~900 cy barrier/LDS chain. Both fixed by halving per-thread
// state: 1024 threads, h[64] + acc[8][2] (64), ALL forced into VGPRs via
// asm MFMA ("v" constraints) -> fits the 16-wave block's hard 128-reg cap
// with zero AGPRs, and gives 4 waves/SIMD.
// This is R1's wave geometry, but R1's LDS-broadcast mv / ybuf (its actual
// failure cause, ~2900 cy/iter LDS pipe) is replaced by the readlane mv +
// pk-FMA + 32-lane update verified in R2-R5. Numerics order-identical.
// Wave (ws=w&7, rh=w>>3) owns H rows 128rh..+127 x cols 32ws..+31; lane l
// holds rows 128rh+2l,+2l+1 interleaved: h[2j+i] = H[128rh+2l+i][32ws+j].
// Both rh waves redundantly compute the update for col-slice ws (keeps
// state wave-private; verified in R1). 1 barrier/iter, ping-pong red.
// (R6 bench attempt died in the container broker, not in the kernel --
// resubmitted unchanged after a full bounds/hang audit.)

namespace {

constexpr int NDIM = 256;
constexpr int NCON = 128;
constexpr int PITERS = 20;
constexpr int FITERS = 100;

typedef short bf16x8 __attribute__((ext_vector_type(8)));
typedef float f32x4  __attribute__((ext_vector_type(4)));
typedef float f32x2  __attribute__((ext_vector_type(2)));

// MFMA with VGPR accumulator (forces zero-AGPR allocation).
#define MFMA_BF16_16x16x32(accv, av, bv)                                  \
    asm volatile("v_mfma_f32_16x16x32_bf16 %0, %1, %2, %0"                \
                 : "+v"(accv) : "v"(av), "v"(bv))

struct Smem {
    union {
        struct {                                 // GEMM phase only
            unsigned short fragHi[16 * 64 * 8];  // 16 KB
            unsigned short fragLo[16 * 64 * 8];  // 16 KB
        };
        float Hbuf[16][32 * 36];                 // 73.7 KB, remap scratch
    };
    float red[2][16][128];                       // 16 KB matvec partials, ping-pong
    float scal[16];
};                                               // ~90 KB < 160 KB

__device__ __forceinline__ unsigned short bf16rne(float x) {
    unsigned u = __float_as_uint(x);
    unsigned r = u + 0x7FFFu + ((u >> 16) & 1u);
    return (unsigned short)(r >> 16);
}

__device__ __forceinline__ float readlane_f(float v, int lane) {
    return __int_as_float(__builtin_amdgcn_readlane(__float_as_int(v), lane));
}

// pw = (partial H x)_{2l,2l+1} over this wave's 32 cols.
// h[2j+i] = H[2l+i][32ws+j] -> one v_pk_fma_f32 per column j.
// x from lanes 0..31's cy via readlane (broadcast, no LDS).
// j ascending -> per-component sum order identical to verified kernels.
__device__ __forceinline__ void mv_pk(const float (&h)[64], float cy,
                                      float* __restrict__ redw, int l)
{
    const f32x2* h2 = (const f32x2*)h;
    f32x2 pw = {0.f, 0.f};
#pragma unroll
    for (int j = 0; j < 32; ++j) {
        float x = readlane_f(cy, j);
        f32x2 xb = {x, x};
        pw = __builtin_elementwise_fma(h2[j], xb, pw);
    }
    *(float2*)(redw + 2 * l) = make_float2(pw.x, pw.y);
}

// sum the 8 col-slice partials; rp points at slice 8*rhp, offset rbase+l.
__device__ __forceinline__ float gather_one(const float* __restrict__ rp)
{
    float s = 0.f;
#pragma unroll
    for (int c = 0; c < 8; ++c) s += rp[c * 128];
    return s;
}

__global__ __launch_bounds__(1024, 4)
void qcqp_fista(const float* __restrict__ P, const float* __restrict__ q,
                const float* __restrict__ ln_, const float* __restrict__ mu,
                float* __restrict__ out)
{
    __shared__ Smem sm;
    const int b = blockIdx.x;
    const int t = threadIdx.x;
    const int w  = t >> 6;        // wave 0..15
    const int l  = t & 63;
    const int ws = w & 7;         // col slice: cols 32ws..32ws+31
    const int rh = w >> 3;        // row half: rows 128rh..128rh+127

    const float* Pb = P + (size_t)b * (NDIM * NDIM);

    // ================== H = P^T P via bf16-split MFMA ==================
    // Staging roles (R1-verified): thread -> (col, k-quad).
    const int col  = t & 255;
    const int qd   = t >> 8;      // 0..3
    const int tile = col >> 4;

    float pf[8];
    auto load_chunk = [&](int cc) {
        const float* src = Pb + (cc * 32 + qd * 8) * 256 + col;
#pragma unroll
        for (int j = 0; j < 8; ++j) pf[j] = src[j * 256];   // coalesced
    };

    f32x4 acc[8][2];
#pragma unroll
    for (int i = 0; i < 8; ++i)
#pragma unroll
        for (int j = 0; j < 2; ++j)
#pragma unroll
            for (int e = 0; e < 4; ++e) acc[i][j][e] = 0.0f;

    load_chunk(0);
    for (int c = 0; c < 8; ++c) {
        unsigned hw[4], lw[4];
#pragma unroll
        for (int jp = 0; jp < 4; ++jp) {
            float f0 = pf[2 * jp], f1 = pf[2 * jp + 1];
            unsigned short h0 = bf16rne(f0), h1 = bf16rne(f1);
            float r0 = f0 - __uint_as_float((unsigned)h0 << 16);
            float r1 = f1 - __uint_as_float((unsigned)h1 << 16);
            unsigned short lo0 = bf16rne(r0), lo1 = bf16rne(r1);
            hw[jp] = (unsigned)h0 | ((unsigned)h1 << 16);
            lw[jp] = (unsigned)lo0 | ((unsigned)lo1 << 16);
        }
        const int slot = tile * 64 + (col & 15) + 16 * qd;
        ((uint4*)sm.fragHi)[slot] = make_uint4(hw[0], hw[1], hw[2], hw[3]);
        ((uint4*)sm.fragLo)[slot] = make_uint4(lw[0], lw[1], lw[2], lw[3]);
        __syncthreads();
        if (c < 7) load_chunk(c + 1);          // prefetch during MFMAs

        const bf16x8* FH = (const bf16x8*)sm.fragHi;
        const bf16x8* FL = (const bf16x8*)sm.fragLo;
        bf16x8 bh0 = FH[(2 * ws) * 64 + l];
        bf16x8 bl0 = FL[(2 * ws) * 64 + l];
        bf16x8 bh1 = FH[(2 * ws + 1) * 64 + l];
        bf16x8 bl1 = FL[(2 * ws + 1) * 64 + l];
#pragma unroll
        for (int tt = 0; tt < 8; ++tt) {
            bf16x8 ah = FH[(8 * rh + tt) * 64 + l];
            bf16x8 al = FL[(8 * rh + tt) * 64 + l];
            MFMA_BF16_16x16x32(acc[tt][0], ah, bh0);
            MFMA_BF16_16x16x32(acc[tt][0], al, bh0);
            MFMA_BF16_16x16x32(acc[tt][0], ah, bl0);
            MFMA_BF16_16x16x32(acc[tt][1], ah, bh1);
            MFMA_BF16_16x16x32(acc[tt][1], al, bh1);
            MFMA_BF16_16x16x32(acc[tt][1], ah, bl1);
        }
        __syncthreads();   // frag reads done before next writes / Hbuf reuse
    }

    // asm MFMA -> VALU/LDS read of acc: supply hazard wait states explicitly.
    asm volatile("s_nop 7\n\ts_nop 7" ::: );

    // ---- acc (C layout: row=16s+4*(l>>4)+reg, col=16*(2ws+tc)+(l&15)) ->
    //      h[2j+i] = H[128rh+2l+i][32ws+j]. Per-rc: acc tiles die as h
    //      fills (owning-lane peak ~ h64 + acc48 + temps < 128).
    //      Intra-wave LDS round trip; same-wave LDS ops are ordered. ----
    const int qd4 = (l >> 4) * 4;
    const int c16 = l & 15;
    float* Hw = sm.Hbuf[w];
    float h[64];
#pragma unroll
    for (int rc = 0; rc < 4; ++rc) {           // local rows 32rc..32rc+31
#pragma unroll
        for (int s = 0; s < 2; ++s)
#pragma unroll
            for (int tc = 0; tc < 2; ++tc)
#pragma unroll
                for (int reg = 0; reg < 4; ++reg)
                    Hw[(16 * s + qd4 + reg) * 36 + 16 * tc + c16] =
                        acc[2 * rc + s][tc][reg];
        if ((l >> 4) == rc) {                   // lanes 16rc..16rc+15
            const int lr = 2 * (l & 15);
#pragma unroll
            for (int i = 0; i < 2; ++i)
#pragma unroll
                for (int jj = 0; jj < 8; ++jj) {
                    float4 v = *(const float4*)&Hw[(lr + i) * 36 + 4 * jj];
                    h[2 * (4 * jj + 0) + i] = v.x;
                    h[2 * (4 * jj + 1) + i] = v.y;
                    h[2 * (4 * jj + 2) + i] = v.z;
                    h[2 * (4 * jj + 3) + i] = v.w;
                }
        }
    }

    // Gather geometry: y comp r = 32ws+l lives in row-half rhp = ws>>2 at
    // slice-local index 32*(ws&3)+l; sum red slices [8*rhp + 0..7].
    const int rhp   = ws >> 2;
    const int rbase = 32 * (ws & 3);

    // ================== power iteration ==================
    // lanes 0..31 hold y comp 32ws+l in cy (identical in both rh waves);
    // x broadcast wave-wide via readlane (no LDS reads in mv).
    float cy = 1.0f;
    int phase = 0;
    for (int it = 0; it < PITERS; ++it, ++phase) {
        mv_pk(h, cy, sm.red[phase & 1][w], l);
        __syncthreads();
        if (l < 32) {
            float s = gather_one(&sm.red[phase & 1][8 * rhp][rbase + l]);
            cy = s * 0.0009765625f;
        }
    }

    // ---- Rayleigh quotient -> step ----
    mv_pk(h, cy, sm.red[phase & 1][w], l);
    __syncthreads();
    float n1 = 0.f, n2 = 0.f;
    if (l < 32) {
        float hv = gather_one(&sm.red[phase & 1][8 * rhp][rbase + l]);
        n1 = cy * hv;
        n2 = cy * cy;
    }
#pragma unroll
    for (int off = 1; off < 64; off <<= 1) {
        n1 += __shfl_xor(n1, off);
        n2 += __shfl_xor(n2, off);
    }
    if (l == 0 && rh == 0) { sm.scal[ws] = n1; sm.scal[8 + ws] = n2; }
    __syncthreads();
    float num = 0.f, den = 0.f;
#pragma unroll
    for (int ww = 0; ww < 8; ++ww) { num += sm.scal[ww]; den += sm.scal[8 + ww]; }
    float L = num / den;
    const float step = 1.0f / (1.05f * fmaxf(L, 1e-12f));
    ++phase;

    // ================== FISTA ==================
    float bq = 0.f, rrv = 0.f, rr2 = 0.f;
    if (l < 32) {
        bq = q[b * NDIM + 32 * ws + l];
        float rv = mu[b * NCON + 16 * ws + (l >> 1)] * ln_[b * NCON + 16 * ws + (l >> 1)];
        rrv = rv;
        rr2 = rv * rv;
    }
    float li = 0.f, tcur = 1.0f;
    cy = 0.0f;                                  // y0 = proj(0) = 0

    for (int it = 0; it < FITERS; ++it, ++phase) {
        mv_pk(h, cy, sm.red[phase & 1][w], l);
        __syncthreads();
        float tn = 0.5f * (1.0f + sqrtf(1.0f + 4.0f * tcur * tcur));
        float ratio = (tcur - 1.0f) / tn;       // off the gather chain
        tcur = tn;
        if (l < 32) {
            float hy = gather_one(&sm.red[phase & 1][8 * rhp][rbase + l]);
            float z  = cy - step * (hy + bq);
            float zz = z * z;
            float n2p = zz + __shfl_xor(zz, 1);  // pair (2p,2p+1) norm^2
            // nrm > rr  <=>  n2p > rr^2 (rr >= 0); scl via 1-ulp HW rsqrt
            float scl = (n2p > rr2) ? (rrv * rsqrtf(n2p)) : 1.0f;
            float l0 = z * scl;
            float yn = l0 + ratio * (l0 - li);
            li = l0;
            cy = yn;
        }
    }

    if (rh == 0 && l < 32)
        out[b * NDIM + 32 * ws + l] = li;
}

} // namespace

extern "C" void kernel_launch(void* const* d_in, const int* in_sizes, int n_in,
                              void* d_out, int out_size, void* d_ws, size_t ws_size,
                              hipStream_t stream) {
    const float* P   = (const float*)d_in[0];
    const float* q   = (const float*)d_in[1];
    const float* l_n = (const float*)d_in[2];
    const float* mu  = (const float*)d_in[3];
    float* out = (float*)d_out;
    qcqp_fista<<<dim3(512), dim3(1024), 0, stream>>>(P, q, l_n, mu, out);
}